// Round 2
// baseline (481.045 us; speedup 1.0000x reference)
//
#include <hip/hip_runtime.h>
#include <hip/hip_bf16.h>

// Problem constants
#define NB 2
#define NN 512
#define HH 128
#define DD 128
#define TT 8

// ws layout (bytes).
#define WPACK_OFF 0        // ushort[16*144*8] = 36864 B, bf16 [k/8][n][k%8]
#define C_OFF     36864    // float[2*512*128]  z@Wm1 + g@Wmg + (bm1+bm2+bme+bmg)
#define BROW_OFF  561152   // float[2*512*128]  z@Wm2
#define TC_OFF    1085440  // float[2*512*8]    z@Wt1 + g@Wtg + (bt1+bt2+bte+btg)
#define TB_OFF    1118208  // float[2*512*8]    z@Wt2
#define OC_OFF    1150976  // float[2*512*128]  z@Wo1 + bo1 + bo2
#define PART_OFF  1675264  // float[2*16*512*128] partial max (no C) per 32-sender chunk
#define ZF_OFF    10063872 // int[2*16*512]     1 if any sender in chunk has adj==0

#define OUT_TRI   131072   // float offset of tri_msgs in d_out

typedef float f32x4 __attribute__((ext_vector_type(4)));
typedef short s16x8 __attribute__((ext_vector_type(8)));

__device__ __forceinline__ unsigned short f2bf(float f) {
    union { float f; unsigned int u; } x; x.f = f;
    unsigned int u = x.u;
    unsigned int r = (u + 0x7FFFu + ((u >> 16) & 1u)) >> 16;  // RNE
    return (unsigned short)r;
}

// packed f32x2 -> bf16x2 (RNE). HW instr v_cvt_pk_bf16_f32 when available.
__device__ __forceinline__ unsigned cvt2bf(float a, float b) {
#if __has_builtin(__builtin_amdgcn_cvt_pk_bf16_f32)
    auto r = __builtin_amdgcn_cvt_pk_bf16_f32(a, b);
    return __builtin_bit_cast(unsigned, r);
#else
    return (unsigned)f2bf(a) | ((unsigned)f2bf(b) << 16);
#endif
}

// async global->LDS DMA, 16B per lane. LDS dest = wave-uniform base + lane*16.
__device__ __forceinline__ void glds16(const float* g, void* l) {
    __builtin_amdgcn_global_load_lds(
        (const __attribute__((address_space(1))) unsigned int*)g,
        (__attribute__((address_space(3))) unsigned int*)l,
        16, 0, 0);
}

// ---------------------------------------------------------------------------
// k0: precompute small projections (fp32) + pack bf16 weights for MFMA
// grid 513 x 256: blocks 0..511 handle 2 rows each; block 512 packs weights.
// ---------------------------------------------------------------------------
__global__ __launch_bounds__(256) void k0_precompute(
    const float* __restrict__ node, const float* __restrict__ hidden,
    const float* __restrict__ graph,
    const float* __restrict__ Wm1, const float* __restrict__ Wm2,
    const float* __restrict__ Wo1, const float* __restrict__ Wmg,
    const float* __restrict__ Wt1, const float* __restrict__ Wt2,
    const float* __restrict__ Wtg,
    const float* __restrict__ Wme, const float* __restrict__ Wte,
    const float* __restrict__ bm1, const float* __restrict__ bm2,
    const float* __restrict__ bme, const float* __restrict__ bmg,
    const float* __restrict__ bo1, const float* __restrict__ bo2,
    const float* __restrict__ bt1, const float* __restrict__ bt2,
    const float* __restrict__ bte, const float* __restrict__ btg,
    char* __restrict__ ws)
{
    const int bx = blockIdx.x, tid = threadIdx.x;
    if (bx == 512) {
        unsigned short* wp = (unsigned short*)(ws + WPACK_OFF);
        for (int idx = tid; idx < 16 * 144 * 8; idx += 256) {
            int j = idx & 7, tmp = idx >> 3;
            int n = tmp % 144, kq = tmp / 144;
            int k = kq * 8 + j;
            float v = 0.f;
            if (n < 128) v = Wme[k * 128 + n];
            else if (n < 136) v = Wte[k * 8 + (n - 128)];
            wp[idx] = f2bf(v);
        }
        return;
    }
    __shared__ float zs[2 * 260];
    const int row0 = bx * 2;       // flat row = b*512 + n
    const int b = row0 >> 9;
    #pragma unroll
    for (int e = 0; e < 2; e++) {
        int idx = e * 256 + tid;
        int rl = idx >> 8, col = idx & 255;
        float v = (col < 128) ? node[(row0 + rl) * 128 + col]
                              : hidden[(row0 + rl) * 128 + col - 128];
        zs[rl * 260 + col] = v;
    }
    __syncthreads();

    float* Cws = (float*)(ws + C_OFF);
    float* Bws = (float*)(ws + BROW_OFF);
    float* Ows = (float*)(ws + OC_OFF);
    float* TCw = (float*)(ws + TC_OFF);
    float* TBw = (float*)(ws + TB_OFF);

    const int d = tid & 127, half = tid >> 7;
    const int row = row0 + half;
    const float* z = zs + half * 260;
    float c = 0.f, q = 0.f, o = 0.f;
    #pragma unroll 8
    for (int k = 0; k < 256; k++) {
        float za = z[k];
        c = fmaf(za, Wm1[k * 128 + d], c);
        q = fmaf(za, Wm2[k * 128 + d], q);
        o = fmaf(za, Wo1[k * 128 + d], o);
    }
    float gm = 0.f;
    #pragma unroll 8
    for (int k = 0; k < 128; k++) gm = fmaf(graph[b * 128 + k], Wmg[k * 128 + d], gm);
    const float cb = gm + bm1[d] + bm2[d] + bme[d] + bmg[d];
    Cws[row * 128 + d] = c + cb;
    Bws[row * 128 + d] = q;
    Ows[row * 128 + d] = o + bo1[d] + bo2[d];

    if (tid < 32) {
        int rl = tid >> 4, t = (tid >> 1) & 7, which = tid & 1;
        const float* zr = zs + rl * 260;
        const float* W = which ? Wt2 : Wt1;
        float acc = 0.f;
        #pragma unroll 8
        for (int k = 0; k < 256; k++) acc = fmaf(zr[k], W[k * 8 + t], acc);
        int rg = row0 + rl;
        if (which == 0) {
            float gt = 0.f;
            #pragma unroll 8
            for (int k = 0; k < 128; k++) gt = fmaf(graph[b * 128 + k], Wtg[k * 8 + t], gt);
            TCw[rg * 8 + t] = acc + gt + bt1[t] + bt2[t] + bte[t] + btg[t];
        } else {
            TBw[rg * 8 + t] = acc;
        }
    }
}

// ---------------------------------------------------------------------------
// k2: fused edge GEMM + tri + masked max.
// A staged via global_load_lds DMA into a 4-buffer LDS ring, prefetched 2
// senders ahead. Raw s_barrier + counted s_waitcnt vmcnt(6) keeps the
// prefetch DMAs in flight ACROSS the barrier (the old __syncthreads emitted
// vmcnt(0) and drained the pipeline every sender -> latency-bound, ~28% of
// HBM roofline). LDS buffers are linear (DMA requirement); bank spread is
// preserved by an XOR chunk swizzle applied to the GLOBAL source address and
// to the ds_read offsets (both-sides-or-neither).
// vmcnt accounting (positional, per wave), audited per iteration:
//  - steady state ii in [1,30]: ops younger than DMA(ii) always include
//    scal(ii-1):4 + DMA(ii+1):2 = 6  -> vmcnt(6) forces DMA(ii), preserves
//    DMA(ii+1) (+ tri stores, which are the newest when present).
//  - ii==0: Bf/Bt/TCf preloads may sit between DMA(0) and the wait ->
//    vmcnt(2) (preserves only DMA(1)).
//  - ii==31: no DMA(32) exists to pad the count -> vmcnt(0).
// scal loads are pinned BEFORE the DMA issue via sched_barrier(0) so the
// compiler's waits for them never target the newest ops (never drain DMA).
// grid (32 jt, 16 ic, 2 b) = 1024 blocks x 256 thr (4 waves), 4 blocks/CU.
// ---------------------------------------------------------------------------
__global__ __launch_bounds__(256, 4) void k2_main(
    const float* __restrict__ edge, const float* __restrict__ adj,
    char* __restrict__ ws, float* __restrict__ out)
{
    __shared__ __align__(16) float As[4][2048];   // 4 x 8 KiB ring, linear
    const int tid = threadIdx.x;
    const int jt = blockIdx.x, ic = blockIdx.y, b = blockIdx.z;
    const int j0 = jt * 16, i0 = ic * 32;

    const int lane = tid & 63, wave = tid >> 6;
    const int quad = lane >> 4, l15 = lane & 15;

    const float* Bws = (const float*)(ws + BROW_OFF);
    const float* TCw = (const float*)(ws + TC_OFF);
    const float* TBw = (const float*)(ws + TB_OFF);
    const s16x8* wp8 = (const s16x8*)(ws + WPACK_OFF);
    float* part = (float*)(ws + PART_OFF);
    int* Zws = (int*)(ws + ZF_OFF);

    // B fragments: 2 D tiles (cols (2*wave+ntl)*16+l15) + tri tile (cols 128+)
    s16x8 Bf[2][4], Bt[4];
    #pragma unroll
    for (int s = 0; s < 4; s++) {
        Bf[0][s] = wp8[(4 * s + quad) * 144 + (2 * wave) * 16 + l15];
        Bf[1][s] = wp8[(4 * s + quad) * 144 + (2 * wave + 1) * 16 + l15];
        Bt[s]    = wp8[(4 * s + quad) * 144 + 128 + l15];
    }

    const int jb = j0 + quad * 4;
    float TCf[4];
    #pragma unroll
    for (int r = 0; r < 4; r++)
        TCf[r] = (l15 < 8) ? TCw[(b * 512 + jb + r) * 8 + l15] : 0.f;

    // DMA addressing. Chunk = 16 B. Buffer is [16 rows][32 chunks] linear;
    // LDS[row][c] holds source chunk (c ^ (row&7)) of that row.
    // Slot 0: chunks 0..255 (rows 0..7), slot 1: 256..511 (rows 8..15).
    const int r0 = tid >> 5;                                 // 0..7
    const int g0 = r0 * 128 + (((tid & 31) ^ (r0 & 7)) << 2); // src float offset
    const int g1 = g0 + 1024;                                 // row+8, same swz
    const int lw = (tid & ~63) << 4;                          // wave-uniform byte base

    const size_t ebase = ((size_t)(b * 512 + i0) * 512 + j0) * 128;

    // prologue: DMA senders 0 (buf0) and 1 (buf1)
    {
        const float* s0p = edge + ebase;
        const float* s1p = edge + ebase + 65536;
        glds16(s0p + g0, (char*)As + lw);
        glds16(s0p + g1, (char*)As + 4096 + lw);
        glds16(s1p + g0, (char*)As + 8192 + lw);
        glds16(s1p + g1, (char*)As + 8192 + 4096 + lw);
    }

    float Mx[2][4];
    #pragma unroll
    for (int ntl = 0; ntl < 2; ntl++)
        #pragma unroll
        for (int r = 0; r < 4; r++) Mx[ntl][r] = -INFINITY;
    int anyz[4] = {0, 0, 0, 0};

    const int c0 = (2 * wave) * 16 + l15, c1 = c0 + 16;
    const int e0 = (2 * quad) ^ (l15 & 7);   // swizzled chunk of first float4

    for (int ii = 0; ii < 32; ii++) {
        // certify my wave's DMA for sender ii retired, then collective go.
        if (ii == 0)      asm volatile("s_waitcnt vmcnt(2)" ::: "memory");
        else if (ii < 31) asm volatile("s_waitcnt vmcnt(6)" ::: "memory");
        else              asm volatile("s_waitcnt vmcnt(0)" ::: "memory");
        __builtin_amdgcn_s_barrier();

        const int ig = i0 + ii;
        const int rowb = b * 512 + ig;

        // 1. this sender's small operands (BEFORE the DMA issue, pinned)
        const float4 adjv = *(const float4*)(adj + (size_t)rowb * 512 + jb);
        const float brw0 = Bws[rowb * 128 + c0];
        const float brw1 = Bws[rowb * 128 + c1];
        const float tb   = TBw[rowb * 8 + (l15 & 7)];
        __builtin_amdgcn_sched_barrier(0);

        // 2. DMA prefetch: sender ii+2 into ring slot (ii+2)&3
        if (ii < 30) {
            const float* sp = edge + ebase + (size_t)(ii + 2) * 65536;
            char* lb = (char*)As + ((ii + 2) & 3) * 8192;
            glds16(sp + g0, lb + lw);
            glds16(sp + g1, lb + 4096 + lw);
        }

        // 3. A fragments from LDS (swizzled read) + cvt to bf16
        const float* bufp = &As[ii & 3][0];
        const float* pA = bufp + l15 * 128 + e0 * 4;
        const float* pB = bufp + l15 * 128 + (e0 ^ 1) * 4;
        s16x8 af[4];
        #pragma unroll
        for (int s = 0; s < 4; s++) {
            float4 pv = *(const float4*)(pA + s * 32);
            float4 qv = *(const float4*)(pB + s * 32);
            union { s16x8 v; unsigned u[4]; } pk;
            pk.u[0] = cvt2bf(pv.x, pv.y);
            pk.u[1] = cvt2bf(pv.z, pv.w);
            pk.u[2] = cvt2bf(qv.x, qv.y);
            pk.u[3] = cvt2bf(qv.z, qv.w);
            af[s] = pk.v;
        }

        // 4. MFMA: 2 D tiles always; tri tile when it's my turn
        f32x4 acc0 = (f32x4){0.f, 0.f, 0.f, 0.f};
        f32x4 acc1 = (f32x4){0.f, 0.f, 0.f, 0.f};
        #pragma unroll
        for (int s = 0; s < 4; s++) {
            acc0 = __builtin_amdgcn_mfma_f32_16x16x32_bf16(af[s], Bf[0][s], acc0, 0, 0, 0);
            acc1 = __builtin_amdgcn_mfma_f32_16x16x32_bf16(af[s], Bf[1][s], acc1, 0, 0, 0);
        }
        const int trimine = ((ii & 3) == wave);
        f32x4 acct = (f32x4){0.f, 0.f, 0.f, 0.f};
        if (trimine) {
            #pragma unroll
            for (int s = 0; s < 4; s++)
                acct = __builtin_amdgcn_mfma_f32_16x16x32_bf16(af[s], Bt[s], acct, 0, 0, 0);
        }

        // 5. tri relu-store on my turn
        if (trimine && l15 < 8) {
            float* tout = out + OUT_TRI + ((size_t)rowb * 512 + jb) * 8 + l15;
            #pragma unroll
            for (int r = 0; r < 4; r++)
                tout[r * 8] = fmaxf(acct[r] + TCf[r] + tb, 0.f);
        }

        // 6. masked-max epilogue (C deferred to k3)
        const float av[4] = {adjv.x, adjv.y, adjv.z, adjv.w};
        #pragma unroll
        for (int r = 0; r < 4; r++) {
            const int isz = (av[r] == 0.f);
            anyz[r] |= isz;
            Mx[0][r] = fmaxf(Mx[0][r], isz ? -INFINITY : (acc0[r] + brw0));
            Mx[1][r] = fmaxf(Mx[1][r], isz ? -INFINITY : (acc1[r] + brw1));
        }
    }

    // store per-chunk partial max — waves own disjoint columns, no reduce
    #pragma unroll
    for (int r = 0; r < 4; r++) {
        const size_t pb = ((size_t)(b * 16 + ic) * 512 + jb + r) * 128;
        part[pb + c0] = Mx[0][r];
        part[pb + c1] = Mx[1][r];
    }
    if (wave == 0 && l15 == 0) {
        #pragma unroll
        for (int r = 0; r < 4; r++)
            Zws[(b * 16 + ic) * 512 + jb + r] = anyz[r];
    }
}

// ---------------------------------------------------------------------------
// k3: msgs = max(max_ic partial + C, anyzero?0:-inf); ret = Oc + msgs @ Wo2
// ---------------------------------------------------------------------------
__global__ __launch_bounds__(128) void k3_final(
    const char* __restrict__ ws, const float* __restrict__ Wo2,
    float* __restrict__ out)
{
    __shared__ float ms[128];
    const int bj = blockIdx.x, d = threadIdx.x;
    const int b = bj >> 9, j = bj & 511;
    const float* part = (const float*)(ws + PART_OFF);
    const int* Zws = (const int*)(ws + ZF_OFF);
    const float* Cws = (const float*)(ws + C_OFF);
    const float* Ows = (const float*)(ws + OC_OFF);

    const int rj = b * 512 + j;
    float m = -INFINITY;
    int zf = 0;
    #pragma unroll
    for (int ic = 0; ic < 16; ic++) {
        m = fmaxf(m, part[((size_t)(b * 16 + ic) * 512 + j) * 128 + d]);
        zf |= Zws[(b * 16 + ic) * 512 + j];
    }
    float c = Cws[rj * 128 + d];
    float mm = fmaxf(m + c, zf ? 0.f : -INFINITY);
    ms[d] = mm;
    __syncthreads();
    float acc = Ows[rj * 128 + d];
    #pragma unroll 8
    for (int k = 0; k < 128; k++) acc = fmaf(ms[k], Wo2[k * 128 + d], acc);
    out[rj * 128 + d] = acc;
}

extern "C" void kernel_launch(void* const* d_in, const int* in_sizes, int n_in,
                              void* d_out, int out_size, void* d_ws, size_t ws_size,
                              hipStream_t stream) {
    const float* node   = (const float*)d_in[0];
    const float* edge   = (const float*)d_in[1];
    const float* graph  = (const float*)d_in[2];
    const float* adj    = (const float*)d_in[3];
    const float* hidden = (const float*)d_in[4];
    const float* Wm1 = (const float*)d_in[5];  const float* bm1 = (const float*)d_in[6];
    const float* Wm2 = (const float*)d_in[7];  const float* bm2 = (const float*)d_in[8];
    const float* Wme = (const float*)d_in[9];  const float* bme = (const float*)d_in[10];
    const float* Wmg = (const float*)d_in[11]; const float* bmg = (const float*)d_in[12];
    const float* Wo1 = (const float*)d_in[13]; const float* bo1 = (const float*)d_in[14];
    const float* Wo2 = (const float*)d_in[15]; const float* bo2 = (const float*)d_in[16];
    const float* Wt1 = (const float*)d_in[17]; const float* bt1 = (const float*)d_in[18];
    const float* Wt2 = (const float*)d_in[19]; const float* bt2 = (const float*)d_in[20];
    const float* Wte = (const float*)d_in[21]; const float* bte = (const float*)d_in[22];
    const float* Wtg = (const float*)d_in[23]; const float* btg = (const float*)d_in[24];
    float* out = (float*)d_out;
    char* ws = (char*)d_ws;

    k0_precompute<<<dim3(513), dim3(256), 0, stream>>>(
        node, hidden, graph, Wm1, Wm2, Wo1, Wmg, Wt1, Wt2, Wtg, Wme, Wte,
        bm1, bm2, bme, bmg, bo1, bo2, bt1, bt2, bte, btg, ws);
    k2_main<<<dim3(32, 16, 2), dim3(256), 0, stream>>>(edge, adj, ws, out);
    k3_final<<<dim3(1024), dim3(128), 0, stream>>>(ws, Wo2, out);
}